// Round 1
// baseline (674.722 us; speedup 1.0000x reference)
//
#include <hip/hip_runtime.h>

#define N_SRC   100000
#define N_TGT   50000
#define N_EDGES 1000000
#define NEG     0.2f
// feature dims: inputs 128, outputs 64

// ---------------------------------------------------------------------------
// K1/K2: row-parallel GEMM  msg = x @ w  (K=128, N=64), plus evec = msg @ a
// block = 256 threads = 4 rows x 64 cols. w (128x64 f32 = 32KB) staged in LDS.
// ---------------------------------------------------------------------------
__global__ __launch_bounds__(256) void gemm_msg(
    const float* __restrict__ x, const float* __restrict__ w,
    const float* __restrict__ att, int att_off,
    float* __restrict__ msg, float* __restrict__ evec)
{
    __shared__ float wls[128 * 64];
    __shared__ float xs[4 * 128];
    const int tid = threadIdx.x;

    // stage w: 8192 floats = 2048 float4, 256 threads -> 8 iters
    #pragma unroll
    for (int i = 0; i < 8; ++i)
        ((float4*)wls)[tid + i * 256] = ((const float4*)w)[tid + i * 256];

    const int row0 = blockIdx.x * 4;
    // stage 4 rows of x: 512 floats = 128 float4
    if (tid < 128)
        ((float4*)xs)[tid] = ((const float4*)(x + (size_t)row0 * 128))[tid];
    __syncthreads();

    const int r = tid >> 6;    // 0..3
    const int c = tid & 63;    // 0..63 (= lane)
    float acc = 0.f;
    #pragma unroll
    for (int k = 0; k < 128; ++k)
        acc += xs[r * 128 + k] * wls[k * 64 + c];

    const int grow = row0 + r;
    msg[(size_t)grow * 64 + c] = acc;

    // evec[grow] = sum_c acc * att[att_off + c]   (full-wave reduce)
    float v = acc * att[att_off + c];
    #pragma unroll
    for (int s = 32; s > 0; s >>= 1)
        v += __shfl_xor(v, s);
    if (c == 0) evec[grow] = v;
}

// ---------------------------------------------------------------------------
// K3: per-edge score + segment-sum denominators (atomics into small arrays)
// ---------------------------------------------------------------------------
__global__ __launch_bounds__(256) void edge_pass1(
    const int* __restrict__ rows, const int* __restrict__ cols,
    const float* __restrict__ es, const float* __restrict__ et,
    float* __restrict__ e_den, float* __restrict__ f_den)
{
    const int i = blockIdx.x * blockDim.x + threadIdx.x;
    if (i >= N_EDGES) return;
    const int r = rows[i], c = cols[i];
    const float s = es[c] + et[r];
    const float v = (s >= 0.f) ? s : NEG * s;
    atomicAdd(&e_den[r], v);
    atomicAdd(&f_den[c], v);
}

// ---------------------------------------------------------------------------
// K4: per-edge weighted message scatter. One wave per edge, lane = feature.
// ---------------------------------------------------------------------------
__global__ __launch_bounds__(256) void edge_pass2(
    const int* __restrict__ rows, const int* __restrict__ cols,
    const float* __restrict__ es, const float* __restrict__ et,
    const float* __restrict__ e_den, const float* __restrict__ f_den,
    const float* __restrict__ nbhd,
    const float* __restrict__ s_msg, const float* __restrict__ t_msg,
    float* __restrict__ msg_src, float* __restrict__ msg_tgt)
{
    const int wid    = (blockIdx.x * blockDim.x + threadIdx.x) >> 6;
    const int lane   = threadIdx.x & 63;
    const int nwaves = (gridDim.x * blockDim.x) >> 6;

    for (int i = wid; i < N_EDGES; i += nwaves) {
        const int r = rows[i], c = cols[i];
        const float s  = es[c] + et[r];
        const float ev = (s >= 0.f) ? s : NEG * s;
        const float nb = nbhd[i];
        const float wst = ev / e_den[r] * nb;
        const float wts = ev / f_den[c] * nb;
        atomicAdd(&msg_tgt[(size_t)r * 64 + lane], wst * s_msg[(size_t)c * 64 + lane]);
        atomicAdd(&msg_src[(size_t)c * 64 + lane], wts * t_msg[(size_t)r * 64 + lane]);
    }
}

// ---------------------------------------------------------------------------
extern "C" void kernel_launch(void* const* d_in, const int* in_sizes, int n_in,
                              void* d_out, int out_size, void* d_ws, size_t ws_size,
                              hipStream_t stream)
{
    const float* x_source = (const float*)d_in[0];
    const float* x_target = (const float*)d_in[1];
    const float* w_s      = (const float*)d_in[2];
    const float* w_t      = (const float*)d_in[3];
    const float* att      = (const float*)d_in[4];
    const float* nbhd     = (const float*)d_in[5];
    const int*   rows     = (const int*)d_in[6];
    const int*   cols     = (const int*)d_in[7];

    float* out     = (float*)d_out;
    float* msg_src = out;                       // (N_SRC, 64)
    float* msg_tgt = out + (size_t)N_SRC * 64;  // (N_TGT, 64)

    float* ws    = (float*)d_ws;
    float* s_msg = ws;                 // 6,400,000 f32
    float* t_msg = ws +  6400000;      // 3,200,000
    float* es    = ws +  9600000;      //   100,000
    float* et    = ws +  9700000;      //    50,000
    float* e_den = ws +  9750000;      //    50,000
    float* f_den = ws +  9800000;      //   100,000
    // total ws use: 9,900,000 f32 = 39.6 MB

    // zero accumulators (harness does not re-poison between replays)
    hipMemsetAsync(out,   0, (size_t)out_size * sizeof(float), stream);
    hipMemsetAsync(e_den, 0, 150000 * sizeof(float), stream);

    gemm_msg<<<N_SRC / 4, 256, 0, stream>>>(x_source, w_s, att, 0,  s_msg, es);
    gemm_msg<<<N_TGT / 4, 256, 0, stream>>>(x_target, w_t, att, 64, t_msg, et);

    edge_pass1<<<(N_EDGES + 255) / 256, 256, 0, stream>>>(rows, cols, es, et, e_den, f_den);

    // 2048 blocks x 4 waves = 8192 waves (full-device resident), ~122 edges each
    edge_pass2<<<2048, 256, 0, stream>>>(rows, cols, es, et, e_den, f_den, nbhd,
                                         s_msg, t_msg, msg_src, msg_tgt);
}